// Round 1
// baseline (59.225 us; speedup 1.0000x reference)
//
#include <hip/hip_runtime.h>
#include <hip/hip_bf16.h>

// Problem constants (match reference)
constexpr int BATCH = 256;
constexpr int NREL  = 16;
constexpr int DIM   = 64;
constexpr int NHOP  = 2;
constexpr int NMEM  = 32;

// One 64-lane wave per (hop, b, r) triple; lane index = embedding dim.
// scores/probs for the 32 memories live redundantly in every lane's registers.
__global__ __launch_bounds__(256)
void kgan_kernel(const float* __restrict__ ent,      // [N_ENT+1, 64]
                 const float* __restrict__ rel,      // [16, 64]
                 const int*   __restrict__ items,    // [256]
                 const int*   __restrict__ mh,       // [2,256,16,32]
                 const int*   __restrict__ mr,
                 const int*   __restrict__ mt,
                 float*       __restrict__ out)      // [2,256,16,64]
{
    const int gtid = blockIdx.x * blockDim.x + threadIdx.x;
    const int wave = gtid >> 6;                // 0 .. NHOP*BATCH*NREL-1
    const int lane = threadIdx.x & 63;         // = dim

    const int r   = wave & (NREL - 1);
    const int b   = (wave >> 4) & (BATCH - 1);
    const int hop = wave >> 12;                // 4+8 bits

    // v = entity_emb[items[b]][lane]
    const int item = items[b];
    const float v = ent[(size_t)item * DIM + lane];

    const int base = ((hop * BATCH + b) * NREL + r) * NMEM;

    float scores[NMEM];
    #pragma unroll
    for (int m = 0; m < NMEM; ++m) {
        const int hid = mh[base + m];
        const int rid = mr[base + m];
        const float h  = ent[(size_t)hid * DIM + lane];
        const float re = rel[rid * DIM + lane];
        float p = re * h * v;
        // full-wave (64-lane) tree reduction
        #pragma unroll
        for (int off = 32; off >= 1; off >>= 1)
            p += __shfl_xor(p, off, 64);
        scores[m] = p;   // every lane holds the full score
    }

    // softmax over the 32 memories (in registers, identical in all lanes)
    float mx = scores[0];
    #pragma unroll
    for (int m = 1; m < NMEM; ++m) mx = fmaxf(mx, scores[m]);

    float sum = 0.f;
    #pragma unroll
    for (int m = 0; m < NMEM; ++m) {
        scores[m] = __expf(scores[m] - mx) ;
        sum += scores[m];
    }
    const float inv = 1.f / sum;

    // o[lane] = sum_m probs[m] * entity_emb[mt[m]][lane]
    float o = 0.f;
    #pragma unroll
    for (int m = 0; m < NMEM; ++m) {
        const int tid = mt[base + m];
        o = fmaf(scores[m] * inv, ent[(size_t)tid * DIM + lane], o);
    }

    out[(size_t)((hop * BATCH + b) * NREL + r) * DIM + lane] = o;
}

extern "C" void kernel_launch(void* const* d_in, const int* in_sizes, int n_in,
                              void* d_out, int out_size, void* d_ws, size_t ws_size,
                              hipStream_t stream) {
    const float* ent   = (const float*)d_in[0];
    const float* rel   = (const float*)d_in[1];
    const int*   items = (const int*)d_in[2];
    const int*   mh    = (const int*)d_in[3];
    const int*   mr    = (const int*)d_in[4];
    const int*   mt    = (const int*)d_in[5];
    float* out = (float*)d_out;

    const int total_waves = NHOP * BATCH * NREL;     // 8192
    const int threads = 256;
    const int blocks = total_waves * 64 / threads;   // 2048

    kgan_kernel<<<blocks, threads, 0, stream>>>(ent, rel, items, mh, mr, mt, out);
}

// Round 2
// 32.503 us; speedup vs baseline: 1.8222x; 1.8222x over previous
//
#include <hip/hip_runtime.h>
#include <hip/hip_bf16.h>

// Problem constants (match reference)
constexpr int BATCH = 256;
constexpr int NREL  = 16;
constexpr int DIM   = 64;
constexpr int NHOP  = 2;
constexpr int NMEM  = 32;

// One 64-lane wave per (hop, b, r) triple; lane index = embedding dim.
// All 96 indices of the triple are loaded in 3 coalesced loads (lane-held),
// broadcast via __shfl (v_readlane). Entity-row gathers are issued in
// 16-wide batches so each wave keeps ~32 loads in flight (latency-bound fix).
__global__ __launch_bounds__(256)
void kgan_kernel(const float* __restrict__ ent,      // [N_ENT+1, 64]
                 const float* __restrict__ rel,      // [16, 64]
                 const int*   __restrict__ items,    // [256]
                 const int*   __restrict__ mh,       // [2,256,16,32]
                 const int*   __restrict__ mr,
                 const int*   __restrict__ mt,
                 float*       __restrict__ out)      // [2,256,16,64]
{
    const int gtid = blockIdx.x * blockDim.x + threadIdx.x;
    const int wave = gtid >> 6;                // 0 .. NHOP*BATCH*NREL-1
    const int lane = threadIdx.x & 63;         // = dim

    const int b = (wave >> 4) & (BATCH - 1);

    // v = entity_emb[items[b]][lane]
    const int item = items[b];
    const float v = ent[(size_t)item * DIM + lane];

    // base for this triple's 32 memories; note wave == ((hop*B+b)*R+r)
    const int base = wave * NMEM;

    // lane-distributed index load: lane l holds index (l & 31)
    const int lm  = lane & 31;
    const int vh  = mh[base + lm];
    const int vr  = mr[base + lm];
    const int vt  = mt[base + lm];

    float sc[NMEM];

    #pragma unroll
    for (int c = 0; c < NMEM; c += 16) {
        float hb[16], rb[16];
        // issue 32 independent loads back-to-back
        #pragma unroll
        for (int j = 0; j < 16; ++j) {
            const int hid = __shfl(vh, c + j, 64);   // v_readlane -> uniform
            const int rid = __shfl(vr, c + j, 64);
            hb[j] = ent[(size_t)hid * DIM + lane];
            rb[j] = rel[rid * DIM + lane];           // 4 KB table, L1-hot
        }
        // consume: dot over 64 lanes per memory
        #pragma unroll
        for (int j = 0; j < 16; ++j) {
            float p = hb[j] * rb[j] * v;
            #pragma unroll
            for (int off = 32; off >= 1; off >>= 1)
                p += __shfl_xor(p, off, 64);
            sc[c + j] = p;                            // all lanes hold score
        }
    }

    // softmax over the 32 memories (registers, identical in all lanes)
    float mx = sc[0];
    #pragma unroll
    for (int m = 1; m < NMEM; ++m) mx = fmaxf(mx, sc[m]);

    float sum = 0.f;
    #pragma unroll
    for (int m = 0; m < NMEM; ++m) {
        sc[m] = __expf(sc[m] - mx);
        sum += sc[m];
    }
    const float inv = 1.f / sum;

    // o[lane] = sum_m probs[m] * entity_emb[mt[m]][lane], 16-wide batched
    float o = 0.f;
    #pragma unroll
    for (int c = 0; c < NMEM; c += 16) {
        float tb[16];
        #pragma unroll
        for (int j = 0; j < 16; ++j) {
            const int tid = __shfl(vt, c + j, 64);
            tb[j] = ent[(size_t)tid * DIM + lane];
        }
        #pragma unroll
        for (int j = 0; j < 16; ++j)
            o = fmaf(sc[c + j] * inv, tb[j], o);
    }

    out[(size_t)wave * DIM + lane] = o;
}

extern "C" void kernel_launch(void* const* d_in, const int* in_sizes, int n_in,
                              void* d_out, int out_size, void* d_ws, size_t ws_size,
                              hipStream_t stream) {
    const float* ent   = (const float*)d_in[0];
    const float* rel   = (const float*)d_in[1];
    const int*   items = (const int*)d_in[2];
    const int*   mh    = (const int*)d_in[3];
    const int*   mr    = (const int*)d_in[4];
    const int*   mt    = (const int*)d_in[5];
    float* out = (float*)d_out;

    const int total_waves = NHOP * BATCH * NREL;     // 8192
    const int threads = 256;
    const int blocks = total_waves * 64 / threads;   // 2048

    kgan_kernel<<<blocks, threads, 0, stream>>>(ent, rel, items, mh, mr, mt, out);
}

// Round 3
// 29.297 us; speedup vs baseline: 2.0215x; 1.1094x over previous
//
#include <hip/hip_runtime.h>
#include <hip/hip_bf16.h>

constexpr int BATCH = 256;
constexpr int NREL  = 16;
constexpr int DIM   = 64;
constexpr int NHOP  = 2;
constexpr int NMEM  = 32;

// One 64-lane wave per (hop,b,r) triple; lane = dim.
// - rel table (4 KB) staged in LDS (frees 32 VGPRs, low-latency reads)
// - all 64 entity-row gathers (32 h + 32 t) issued up front -> max MLP
// - pairwise-folded wave reduction: scores packed 2-per-register
//   (lanes<32 hold even memories, lanes>=32 odd)
__global__ __launch_bounds__(256)
void kgan_kernel(const float* __restrict__ ent,      // [N_ENT+1, 64]
                 const float* __restrict__ rel,      // [16, 64]
                 const int*   __restrict__ items,    // [256]
                 const int*   __restrict__ mh,
                 const int*   __restrict__ mr,
                 const int*   __restrict__ mt,
                 float*       __restrict__ out)      // [2,256,16,64]
{
    __shared__ float rel_lds[NREL * DIM];            // 4 KB
    {
        // 256 threads x float4 = 1024 floats
        const int t = threadIdx.x;
        reinterpret_cast<float4*>(rel_lds)[t] =
            reinterpret_cast<const float4*>(rel)[t];
    }
    __syncthreads();

    const int gtid = blockIdx.x * blockDim.x + threadIdx.x;
    const int wave = gtid >> 6;                // (hop*B + b)*R + r
    const int lane = threadIdx.x & 63;         // = dim

    const int b = (wave >> 4) & (BATCH - 1);

    const int item = items[b];
    const float v = ent[(size_t)item * DIM + lane];

    const int base = wave * NMEM;
    const int lm   = lane & 31;
    const int vh   = mh[base + lm];            // lane-distributed indices
    const int vr   = mr[base + lm];
    const int vt   = mt[base + lm];

    // ---- issue ALL 64 entity gathers up front ----
    float hb[NMEM], tb[NMEM];
    #pragma unroll
    for (int m = 0; m < NMEM; ++m) {
        const int hid = __shfl(vh, m, 64);     // v_readlane (imm lane)
        hb[m] = ent[(size_t)hid * DIM + lane];
    }
    #pragma unroll
    for (int m = 0; m < NMEM; ++m) {
        const int tid = __shfl(vt, m, 64);
        tb[m] = ent[(size_t)tid * DIM + lane];
    }

    // ---- QK^T: pairwise-folded 64-lane reductions ----
    // scp[j]: lanes<32 hold score(2j), lanes>=32 hold score(2j+1)
    float scp[NMEM / 2];
    const bool hi = (lane & 32) != 0;
    #pragma unroll
    for (int j = 0; j < NMEM / 2; ++j) {
        const int r0 = __shfl(vr, 2 * j, 64);
        const int r1 = __shfl(vr, 2 * j + 1, 64);
        float a = hb[2 * j]     * rel_lds[r0 * DIM + lane] * v;
        float c = hb[2 * j + 1] * rel_lds[r1 * DIM + lane] * v;
        a += __shfl_xor(a, 32, 64);
        c += __shfl_xor(c, 32, 64);
        float p = hi ? c : a;                  // fold 2 memories into halves
        #pragma unroll
        for (int off = 16; off >= 1; off >>= 1)
            p += __shfl_xor(p, off, 64);
        scp[j] = p;
    }

    // ---- softmax over 32 memories (packed: 16 values/lane) ----
    float mx = scp[0];
    #pragma unroll
    for (int j = 1; j < NMEM / 2; ++j) mx = fmaxf(mx, scp[j]);
    mx = fmaxf(mx, __shfl_xor(mx, 32, 64));

    float sum = 0.f;
    #pragma unroll
    for (int j = 0; j < NMEM / 2; ++j) {
        scp[j] = __expf(scp[j] - mx);
        sum += scp[j];
    }
    sum += __shfl_xor(sum, 32, 64);
    const float inv = 1.f / sum;

    // ---- PV: unpack pair probs with 1 shfl + selects ----
    float o = 0.f;
    #pragma unroll
    for (int j = 0; j < NMEM / 2; ++j) {
        const float pc = scp[j] * inv;                 // this half's memory
        const float po = __shfl_xor(pc, 32, 64);       // other memory
        const float te = tb[2 * j], to_ = tb[2 * j + 1];
        const float t1 = hi ? to_ : te;                // pairs with pc
        const float t2 = hi ? te  : to_;               // pairs with po
        o = fmaf(pc, t1, o);
        o = fmaf(po, t2, o);
    }

    out[(size_t)wave * DIM + lane] = o;
}

extern "C" void kernel_launch(void* const* d_in, const int* in_sizes, int n_in,
                              void* d_out, int out_size, void* d_ws, size_t ws_size,
                              hipStream_t stream) {
    const float* ent   = (const float*)d_in[0];
    const float* rel   = (const float*)d_in[1];
    const int*   items = (const int*)d_in[2];
    const int*   mh    = (const int*)d_in[3];
    const int*   mr    = (const int*)d_in[4];
    const int*   mt    = (const int*)d_in[5];
    float* out = (float*)d_out;

    const int total_waves = NHOP * BATCH * NREL;     // 8192
    const int threads = 256;
    const int blocks = total_waves * 64 / threads;   // 2048

    kgan_kernel<<<blocks, threads, 0, stream>>>(ent, rel, items, mh, mr, mt, out);
}

// Round 4
// 25.350 us; speedup vs baseline: 2.3363x; 1.1557x over previous
//
#include <hip/hip_runtime.h>
#include <hip/hip_bf16.h>

constexpr int BATCH = 256;
constexpr int NREL  = 16;
constexpr int DIM   = 64;
constexpr int NHOP  = 2;
constexpr int NMEM  = 32;

// One 64-lane wave per (hop,b,r) triple.
// Lane remap: sub = lane>>4 selects one of 4 rows per gather batch,
//             q   = lane&15 selects the float4 within the 256 B row.
// -> each global_load_dwordx4 fetches FOUR entity rows (1 KB): 4x fewer
//    VMEM instructions, 16-lane (4-step) reductions instead of 64-lane.
__global__ __launch_bounds__(256)
void kgan_kernel(const float* __restrict__ ent,      // [N_ENT+1, 64]
                 const float* __restrict__ rel,      // [16, 64]
                 const int*   __restrict__ items,    // [256]
                 const int*   __restrict__ mh,
                 const int*   __restrict__ mr,
                 const int*   __restrict__ mt,
                 float*       __restrict__ out)      // [2,256,16,64]
{
    __shared__ float rel_lds[NREL * DIM];            // 4 KB
    {
        const int t = threadIdx.x;                   // 256 threads x float4
        reinterpret_cast<float4*>(rel_lds)[t] =
            reinterpret_cast<const float4*>(rel)[t];
    }
    __syncthreads();

    const int gtid = blockIdx.x * blockDim.x + threadIdx.x;
    const int wave = gtid >> 6;                // (hop*B + b)*R + r
    const int lane = threadIdx.x & 63;
    const int sub  = lane >> 4;                // 0..3  (row within batch of 4)
    const int q    = lane & 15;                // 0..15 (float4 within row)

    const int b = (wave >> 4) & (BATCH - 1);

    // v4 = item embedding, dims [4q .. 4q+3] (replicated across subs)
    const int item = items[b];
    const float4 v4 = reinterpret_cast<const float4*>(ent)[(size_t)item * 16 + q];

    const int base = wave * NMEM;
    const int lm   = lane & 31;
    const int vh   = mh[base + lm];            // lane-distributed indices
    const int vr   = mr[base + lm];
    const int vt   = mt[base + lm];

    const float4* ent4 = reinterpret_cast<const float4*>(ent);
    const float4* rl4  = reinterpret_cast<const float4*>(rel_lds);

    // ---- issue all 16 h/t gathers (4 rows each) up front ----
    float4 hb[8], tb[8];
    int ridx[8];
    #pragma unroll
    for (int j = 0; j < 8; ++j) {
        const int hid = __shfl(vh, 4 * j + sub, 64);   // ds_bpermute
        hb[j] = ent4[(size_t)hid * 16 + q];
    }
    #pragma unroll
    for (int j = 0; j < 8; ++j) {
        const int tid = __shfl(vt, 4 * j + sub, 64);
        tb[j] = ent4[(size_t)tid * 16 + q];
    }
    #pragma unroll
    for (int j = 0; j < 8; ++j)
        ridx[j] = __shfl(vr, 4 * j + sub, 64);

    // ---- scores: lane computes dot4 for memory (4j+sub), reduce over q ----
    float sc[8];
    #pragma unroll
    for (int j = 0; j < 8; ++j) {
        const float4 r4 = rl4[ridx[j] * 16 + q];
        const float4 h4 = hb[j];
        float p = h4.x * r4.x * v4.x;
        p = fmaf(h4.y * r4.y, v4.y, p);
        p = fmaf(h4.z * r4.z, v4.z, p);
        p = fmaf(h4.w * r4.w, v4.w, p);
        #pragma unroll
        for (int off = 8; off >= 1; off >>= 1)       // 16-lane group reduce
            p += __shfl_xor(p, off, 64);
        sc[j] = p;                                    // score(4j+sub), all q
    }

    // ---- softmax over 32 memories ----
    float mx = sc[0];
    #pragma unroll
    for (int j = 1; j < 8; ++j) mx = fmaxf(mx, sc[j]);
    mx = fmaxf(mx, __shfl_xor(mx, 16, 64));           // cross-sub
    mx = fmaxf(mx, __shfl_xor(mx, 32, 64));

    float sum = 0.f;
    #pragma unroll
    for (int j = 0; j < 8; ++j) {
        sc[j] = __expf(sc[j] - mx);
        sum += sc[j];
    }
    sum += __shfl_xor(sum, 16, 64);
    sum += __shfl_xor(sum, 32, 64);
    const float inv = 1.f / sum;

    // ---- PV: acc4 = sum_j p(4j+sub) * t(4j+sub)[4q..4q+3] ----
    float4 acc = make_float4(0.f, 0.f, 0.f, 0.f);
    #pragma unroll
    for (int j = 0; j < 8; ++j) {
        const float p = sc[j] * inv;
        acc.x = fmaf(p, tb[j].x, acc.x);
        acc.y = fmaf(p, tb[j].y, acc.y);
        acc.z = fmaf(p, tb[j].z, acc.z);
        acc.w = fmaf(p, tb[j].w, acc.w);
    }
    // cross-sub reduce (4 components x 2 steps)
    acc.x += __shfl_xor(acc.x, 16, 64);
    acc.y += __shfl_xor(acc.y, 16, 64);
    acc.z += __shfl_xor(acc.z, 16, 64);
    acc.w += __shfl_xor(acc.w, 16, 64);
    acc.x += __shfl_xor(acc.x, 32, 64);
    acc.y += __shfl_xor(acc.y, 32, 64);
    acc.z += __shfl_xor(acc.z, 32, 64);
    acc.w += __shfl_xor(acc.w, 32, 64);

    if (sub == 0)
        reinterpret_cast<float4*>(out)[(size_t)wave * 16 + q] = acc;
}

extern "C" void kernel_launch(void* const* d_in, const int* in_sizes, int n_in,
                              void* d_out, int out_size, void* d_ws, size_t ws_size,
                              hipStream_t stream) {
    const float* ent   = (const float*)d_in[0];
    const float* rel   = (const float*)d_in[1];
    const int*   items = (const int*)d_in[2];
    const int*   mh    = (const int*)d_in[3];
    const int*   mr    = (const int*)d_in[4];
    const int*   mt    = (const int*)d_in[5];
    float* out = (float*)d_out;

    const int total_waves = NHOP * BATCH * NREL;     // 8192
    const int threads = 256;
    const int blocks = total_waves * 64 / threads;   // 2048

    kgan_kernel<<<blocks, threads, 0, stream>>>(ent, rel, items, mh, mr, mt, out);
}